// Round 6
// baseline (131.996 us; speedup 1.0000x reference)
//
#include <hip/hip_runtime.h>
#include <hip/hip_bf16.h>
#include <stdint.h>

#define N_ROWS 16384
#define O_ROWS 1024
#define K_DIM  512

typedef __bf16 bf16x4 __attribute__((ext_vector_type(4)));
typedef __bf16 bf16x8 __attribute__((ext_vector_type(8)));
typedef float  f32x4  __attribute__((ext_vector_type(4)));

__device__ __forceinline__ ushort f2bfu(float f) {
    __bf16 h = (__bf16)f;
    return __builtin_bit_cast(ushort, h);
}

// ---------------------------------------------------------------------------
// Round 6 = round 5 numerics + three counter-driven fixes:
//  (T2) XOR-swizzle sA/sB: byte ^= ((row&7)<<4) on both ds_write and ds_read
//       kills the 16-way bank conflict on fragment reads (6.4M conflict cyc).
//  (LDS) extra K-tiles aliased into sA's storage (only live after the main
//       loop) -> LDS 48->32 KB -> 5 blocks/CU instead of 3.
//  (T1) bijective XCD swizzle (1024 tiles, %8==0): the 8 col-tiles sharing an
//       x row-panel run on one XCD's L2 -> x fetched ~once instead of ~4x.
// d2 still computed entirely in the MFMA accumulator via the extended K-tile:
//   A_ext=[x_bf16 | xsq,1,0..], B_ext=[-2m_bf16 | 1,msq,0..]; out=rsqrt(acc).
// ---------------------------------------------------------------------------
__global__ __launch_bounds__(256, 5) void quadra_kernel(
    const float* __restrict__ x, const float* __restrict__ mean,
    float* __restrict__ out)
{
    __shared__ ushort sA[128 * 64];   // [row][k] bf16 (swizzled), 16 KiB
    __shared__ ushort sB[128 * 64];   // [orow][k] bf16 -2*mean (swizzled), 16 KiB
    // extra tiles alias sA after the main loop: sAe = sA[0:4096], sBe = sA[4096:8192]

    // XCD swizzle: chunk c=bid&7 gets tiles t=c*128+i; row=t>>3, col=t&7 so
    // 8 consecutive tiles in a chunk share one x row-panel.
    const int bid  = blockIdx.x;                // 0..1023
    const int t    = (bid & 7) * 128 + (bid >> 3);
    const int brow = (t >> 3) * 128;
    const int bcol = (t & 7) * 128;

    const int tid  = threadIdx.x;
    const int lane = tid & 63;
    const int wid  = tid >> 6;
    const int wr = wid >> 1, wc = wid & 1;      // 2x2 wave grid, 64x64 out each

    f32x4 acc[4][4] = {};

    // staging: seg = tid>>4 (0..15), q = tid&15.
    // thread stages rows {r8*16+seg}, k-quad [q*4, q*4+4) per 64-wide tile.
    const int seg = tid >> 4;
    const int q   = tid & 15;

    const float* gA = x    + (size_t)(brow + seg) * K_DIM + q * 4;
    const float* gB = mean + (size_t)(bcol + seg) * K_DIM + q * 4;

    float asq[8], bsq[8];
    #pragma unroll
    for (int i = 0; i < 8; ++i) { asq[i] = 0.f; bsq[i] = 0.f; }

    for (int kt = 0; kt < K_DIM / 64; ++kt) {
        #pragma unroll
        for (int r8 = 0; r8 < 8; ++r8) {
            f32x4 va = *(const f32x4*)(gA + (size_t)(r8 * 16) * K_DIM + kt * 64);
            f32x4 vb = *(const f32x4*)(gB + (size_t)(r8 * 16) * K_DIM + kt * 64);

            asq[r8] += va[0]*va[0] + va[1]*va[1] + va[2]*va[2] + va[3]*va[3];
            bsq[r8] += vb[0]*vb[0] + vb[1]*vb[1] + vb[2]*vb[2] + vb[3]*vb[3];

            bf16x4 ca, cb;
            ca[0] = (__bf16)va[0]; ca[1] = (__bf16)va[1];
            ca[2] = (__bf16)va[2]; ca[3] = (__bf16)va[3];
            cb[0] = (__bf16)(vb[0] * -2.0f); cb[1] = (__bf16)(vb[1] * -2.0f);
            cb[2] = (__bf16)(vb[2] * -2.0f); cb[3] = (__bf16)(vb[3] * -2.0f);

            // T2 swizzle: byte-within-row ^= ((row&7)<<4); 8B writes stay
            // inside one 16B slot, so the XOR is write-contiguity-safe.
            const int row  = r8 * 16 + seg;
            const int wb   = (q * 8) ^ ((row & 7) << 4);   // byte offset in row
            *(bf16x4*)(sA + row * 64 + (wb >> 1)) = ca;
            *(bf16x4*)(sB + row * 64 + (wb >> 1)) = cb;
        }
        __syncthreads();

        #pragma unroll
        for (int ks = 0; ks < 2; ++ks) {
            bf16x8 a[4], b[4];
            const int hi = lane >> 4, cl = lane & 15;
            #pragma unroll
            for (int m = 0; m < 4; ++m) {
                const int row = wr*64 + m*16 + cl;
                const int rb  = (ks*64 + hi*16) ^ ((row & 7) << 4);
                a[m] = *(const bf16x8*)(sA + row * 64 + (rb >> 1));
            }
            #pragma unroll
            for (int n = 0; n < 4; ++n) {
                const int row = wc*64 + n*16 + cl;
                const int rb  = (ks*64 + hi*16) ^ ((row & 7) << 4);
                b[n] = *(const bf16x8*)(sB + row * 64 + (rb >> 1));
            }
            #pragma unroll
            for (int m = 0; m < 4; ++m)
                #pragma unroll
                for (int n = 0; n < 4; ++n)
                    acc[m][n] = __builtin_amdgcn_mfma_f32_16x16x32_bf16(
                        a[m], b[n], acc[m][n], 0, 0, 0);
        }
        __syncthreads();
    }

    // Extended K-tile (aliased into sA, which is dead now). Unswizzled:
    // read once, conflict cost negligible. Every thread writes (q!=0 -> 0s):
    //   sAe[row] = [xsq, 1, 0 x30]   sBe[row] = [1, msq, 0 x30]
    ushort* sAe = sA;
    ushort* sBe = sA + 128 * 32;
    #pragma unroll
    for (int r8 = 0; r8 < 8; ++r8) {
        float sa = asq[r8], sb = bsq[r8];
        #pragma unroll
        for (int msk = 1; msk < 16; msk <<= 1) {
            sa += __shfl_xor(sa, msk);
            sb += __shfl_xor(sb, msk);
        }
        const int row = r8 * 16 + seg;
        uint32_t aw = 0, bw = 0;
        if (q == 0) {
            aw = (uint32_t)f2bfu(sa) | (0x3F80u << 16);   // [xsq, 1.0]
            bw = 0x3F80u | ((uint32_t)f2bfu(sb) << 16);   // [1.0, msq]
        }
        *(uint32_t*)(sAe + row * 32 + q * 2) = aw;
        *(uint32_t*)(sBe + row * 32 + q * 2) = bw;
    }
    __syncthreads();

    {   // extra MFMA: adds xsq[r] + msq[o] into every accumulator element
        bf16x8 a[4], b[4];
        #pragma unroll
        for (int m = 0; m < 4; ++m)
            a[m] = *(const bf16x8*)(sAe + (wr*64 + m*16 + (lane & 15)) * 32
                                        + (lane >> 4) * 8);
        #pragma unroll
        for (int n = 0; n < 4; ++n)
            b[n] = *(const bf16x8*)(sBe + (wc*64 + n*16 + (lane & 15)) * 32
                                        + (lane >> 4) * 8);
        #pragma unroll
        for (int m = 0; m < 4; ++m)
            #pragma unroll
            for (int n = 0; n < 4; ++n)
                acc[m][n] = __builtin_amdgcn_mfma_f32_16x16x32_bf16(
                    a[m], b[n], acc[m][n], 0, 0, 0);
    }

    // epilogue: C/D layout col = lane&15, row = (lane>>4)*4 + j
    const int cl = lane & 15, rg = lane >> 4;
    #pragma unroll
    for (int m = 0; m < 4; ++m) {
        #pragma unroll
        for (int j = 0; j < 4; ++j) {
            const int grow = brow + wr*64 + m*16 + rg*4 + j;
            float* orow = out + (size_t)grow * O_ROWS + bcol + wc*64 + cl;
            #pragma unroll
            for (int n = 0; n < 4; ++n)
                orow[n * 16] = rsqrtf(acc[m][n][j]);
        }
    }
}

extern "C" void kernel_launch(void* const* d_in, const int* in_sizes, int n_in,
                              void* d_out, int out_size, void* d_ws, size_t ws_size,
                              hipStream_t stream) {
    const float* x    = (const float*)d_in[0];
    const float* mean = (const float*)d_in[1];
    float* out = (float*)d_out;

    quadra_kernel<<<dim3((N_ROWS / 128) * (O_ROWS / 128)), 256, 0, stream>>>(
        x, mean, out);
}

// Round 9
// 55.141 us; speedup vs baseline: 2.3938x; 2.3938x over previous
//
#include <hip/hip_runtime.h>
#include <hip/hip_bf16.h>
#include <stdint.h>

#define N_ROWS 16384
#define O_ROWS 1024
#define K_DIM  512

typedef __bf16 bf16x4 __attribute__((ext_vector_type(4)));
typedef __bf16 bf16x8 __attribute__((ext_vector_type(8)));
typedef float  f32x4  __attribute__((ext_vector_type(4)));

__device__ __forceinline__ ushort f2bfu(float f) {
    __bf16 h = (__bf16)f;
    return __builtin_bit_cast(ushort, h);
}

// ---------------------------------------------------------------------------
// Round 9 = round 7 resubmitted verbatim (r7/r8 both died to an unresponsive
// MI355X container before the bench could run).
//  - __launch_bounds__(256) ONLY: r6's (256,5) forced VGPR 96->48 and spilled
//    the accumulators (WRITE_SIZE 65->405 MB). Natural allocation (~96 VGPR)
//    already permits 5 waves/EU; LDS 32 KB permits 5 blocks/CU.
//  - T2 XOR-swizzle kept (bank conflicts 6.4M -> 131K, verified r6).
//  - Extra-K-tile aliasing kept (LDS 32 KB).
//  - XCD swizzle kept.
// d2 computed entirely in the MFMA accumulator via the extended K-tile:
//   A_ext=[x_bf16 | xsq,1,0..], B_ext=[-2m_bf16 | 1,msq,0..]; out=rsqrt(acc).
// ---------------------------------------------------------------------------
__global__ __launch_bounds__(256) void quadra_kernel(
    const float* __restrict__ x, const float* __restrict__ mean,
    float* __restrict__ out)
{
    __shared__ ushort sA[128 * 64];   // [row][k] bf16 (swizzled), 16 KiB
    __shared__ ushort sB[128 * 64];   // [orow][k] bf16 -2*mean (swizzled), 16 KiB
    // extra tiles alias sA after the main loop

    const int bid  = blockIdx.x;                // 0..1023
    const int t    = (bid & 7) * 128 + (bid >> 3);
    const int brow = (t >> 3) * 128;
    const int bcol = (t & 7) * 128;

    const int tid  = threadIdx.x;
    const int lane = tid & 63;
    const int wid  = tid >> 6;
    const int wr = wid >> 1, wc = wid & 1;      // 2x2 wave grid, 64x64 out each

    f32x4 acc[4][4] = {};

    const int seg = tid >> 4;
    const int q   = tid & 15;

    const float* gA = x    + (size_t)(brow + seg) * K_DIM + q * 4;
    const float* gB = mean + (size_t)(bcol + seg) * K_DIM + q * 4;

    float asq[8], bsq[8];
    #pragma unroll
    for (int i = 0; i < 8; ++i) { asq[i] = 0.f; bsq[i] = 0.f; }

    for (int kt = 0; kt < K_DIM / 64; ++kt) {
        #pragma unroll
        for (int r8 = 0; r8 < 8; ++r8) {
            f32x4 va = *(const f32x4*)(gA + (size_t)(r8 * 16) * K_DIM + kt * 64);
            f32x4 vb = *(const f32x4*)(gB + (size_t)(r8 * 16) * K_DIM + kt * 64);

            asq[r8] += va[0]*va[0] + va[1]*va[1] + va[2]*va[2] + va[3]*va[3];
            bsq[r8] += vb[0]*vb[0] + vb[1]*vb[1] + vb[2]*vb[2] + vb[3]*vb[3];

            bf16x4 ca, cb;
            ca[0] = (__bf16)va[0]; ca[1] = (__bf16)va[1];
            ca[2] = (__bf16)va[2]; ca[3] = (__bf16)va[3];
            cb[0] = (__bf16)(vb[0] * -2.0f); cb[1] = (__bf16)(vb[1] * -2.0f);
            cb[2] = (__bf16)(vb[2] * -2.0f); cb[3] = (__bf16)(vb[3] * -2.0f);

            const int row  = r8 * 16 + seg;
            const int wb   = (q * 8) ^ ((row & 7) << 4);   // byte offset in row
            *(bf16x4*)(sA + row * 64 + (wb >> 1)) = ca;
            *(bf16x4*)(sB + row * 64 + (wb >> 1)) = cb;
        }
        __syncthreads();

        #pragma unroll
        for (int ks = 0; ks < 2; ++ks) {
            bf16x8 a[4], b[4];
            const int hi = lane >> 4, cl = lane & 15;
            #pragma unroll
            for (int m = 0; m < 4; ++m) {
                const int row = wr*64 + m*16 + cl;
                const int rb  = (ks*64 + hi*16) ^ ((row & 7) << 4);
                a[m] = *(const bf16x8*)(sA + row * 64 + (rb >> 1));
            }
            #pragma unroll
            for (int n = 0; n < 4; ++n) {
                const int row = wc*64 + n*16 + cl;
                const int rb  = (ks*64 + hi*16) ^ ((row & 7) << 4);
                b[n] = *(const bf16x8*)(sB + row * 64 + (rb >> 1));
            }
            #pragma unroll
            for (int m = 0; m < 4; ++m)
                #pragma unroll
                for (int n = 0; n < 4; ++n)
                    acc[m][n] = __builtin_amdgcn_mfma_f32_16x16x32_bf16(
                        a[m], b[n], acc[m][n], 0, 0, 0);
        }
        __syncthreads();
    }

    // Extended K-tile (aliased into sA, dead after the main loop).
    ushort* sAe = sA;
    ushort* sBe = sA + 128 * 32;
    #pragma unroll
    for (int r8 = 0; r8 < 8; ++r8) {
        float sa = asq[r8], sb = bsq[r8];
        #pragma unroll
        for (int msk = 1; msk < 16; msk <<= 1) {
            sa += __shfl_xor(sa, msk);
            sb += __shfl_xor(sb, msk);
        }
        const int row = r8 * 16 + seg;
        uint32_t aw = 0, bw = 0;
        if (q == 0) {
            aw = (uint32_t)f2bfu(sa) | (0x3F80u << 16);   // [xsq, 1.0]
            bw = 0x3F80u | ((uint32_t)f2bfu(sb) << 16);   // [1.0, msq]
        }
        *(uint32_t*)(sAe + row * 32 + q * 2) = aw;
        *(uint32_t*)(sBe + row * 32 + q * 2) = bw;
    }
    __syncthreads();

    {   // extra MFMA: adds xsq[r] + msq[o] into every accumulator element
        bf16x8 a[4], b[4];
        #pragma unroll
        for (int m = 0; m < 4; ++m)
            a[m] = *(const bf16x8*)(sAe + (wr*64 + m*16 + (lane & 15)) * 32
                                        + (lane >> 4) * 8);
        #pragma unroll
        for (int n = 0; n < 4; ++n)
            b[n] = *(const bf16x8*)(sBe + (wc*64 + n*16 + (lane & 15)) * 32
                                        + (lane >> 4) * 8);
        #pragma unroll
        for (int m = 0; m < 4; ++m)
            #pragma unroll
            for (int n = 0; n < 4; ++n)
                acc[m][n] = __builtin_amdgcn_mfma_f32_16x16x32_bf16(
                    a[m], b[n], acc[m][n], 0, 0, 0);
    }

    // epilogue: C/D layout col = lane&15, row = (lane>>4)*4 + j
    const int cl = lane & 15, rg = lane >> 4;
    #pragma unroll
    for (int m = 0; m < 4; ++m) {
        #pragma unroll
        for (int j = 0; j < 4; ++j) {
            const int grow = brow + wr*64 + m*16 + rg*4 + j;
            float* orow = out + (size_t)grow * O_ROWS + bcol + wc*64 + cl;
            #pragma unroll
            for (int n = 0; n < 4; ++n)
                orow[n * 16] = rsqrtf(acc[m][n][j]);
        }
    }
}

extern "C" void kernel_launch(void* const* d_in, const int* in_sizes, int n_in,
                              void* d_out, int out_size, void* d_ws, size_t ws_size,
                              hipStream_t stream) {
    const float* x    = (const float*)d_in[0];
    const float* mean = (const float*)d_in[1];
    float* out = (float*)d_out;

    quadra_kernel<<<dim3((N_ROWS / 128) * (O_ROWS / 128)), 256, 0, stream>>>(
        x, mean, out);
}